// Round 7
// baseline (848.087 us; speedup 1.0000x reference)
//
#include <hip/hip_runtime.h>
#include <stdint.h>

// ---------------- problem constants ----------------
#define NTOK   16384      // B*S
#define HDIM   1024
#define IDIM   2048
#define NEXP   8
#define NASG   (NTOK*2)   // top-2 assignments
#define RBLK   512        // router grid blocks (2 per CU)

typedef __bf16 bf16x8 __attribute__((ext_vector_type(8)));
typedef float  f32x4  __attribute__((ext_vector_type(4)));

__device__ __forceinline__ unsigned short f2b(float f) {
  unsigned int u = __builtin_bit_cast(unsigned int, f);
  u = (u + 0x7fffu + ((u >> 16) & 1u)) >> 16;   // RNE
  return (unsigned short)u;
}

__device__ __forceinline__ void async16(const void* g, void* l) {
  // global -> LDS DMA, 16B/lane. LDS dest is wave-uniform base + lane*16.
  __builtin_amdgcn_global_load_lds(
      (__attribute__((address_space(1))) void*)(uintptr_t)g,
      (__attribute__((address_space(3))) void*)l,
      16, 0, 0);
}

__device__ __forceinline__ bf16x8 load_frag(const unsigned short* p) {
  uint4 v = *(const uint4*)p;
  return __builtin_bit_cast(bf16x8, v);
}

// ---------------- cast fp32 -> bf16 ----------------
__global__ __launch_bounds__(256) void cast_kernel(const float* __restrict__ in,
                                                   unsigned short* __restrict__ out,
                                                   int n4) {
  int i = blockIdx.x * blockDim.x + threadIdx.x;
  int stride = gridDim.x * blockDim.x;
  for (; i < n4; i += stride) {
    float4 v = ((const float4*)in)[i];
    ushort4 o;
    o.x = f2b(v.x); o.y = f2b(v.y); o.z = f2b(v.z); o.w = f2b(v.w);
    ((ushort4*)out)[i] = o;
  }
}

// ---------------- router: grid-stride waves, 16-bin (e,slot) LDS histogram ----
// Slot-partitioned counting: bin = e*2 + slot, so scatter can place each
// expert's slot-0 rows before its slot-1 rows. This lets gemm2 write out
// with NO atomics (pass0 plain-store covers every token once; pass1 adds).
__global__ __launch_bounds__(256) void router_kernel(const float* __restrict__ x,
                                                     const float* __restrict__ rw,
                                                     unsigned short* __restrict__ xb,
                                                     int* __restrict__ tok_e,
                                                     float* __restrict__ tok_w,
                                                     int* __restrict__ hist) {
  __shared__ float srw[NEXP * HDIM];   // 32 KB: router weights, read 8x per token
  __shared__ int hcnt[NEXP * 2];
  int tid = threadIdx.x;
  for (int i = tid; i < (NEXP * HDIM) / 4; i += 256)
    ((float4*)srw)[i] = ((const float4*)rw)[i];
  if (tid < NEXP * 2) hcnt[tid] = 0;
  __syncthreads();

  int wid = tid >> 6, lane = tid & 63;
  int gwave = blockIdx.x * 4 + wid;
  int nw = RBLK * 4;
  for (int t = gwave; t < NTOK; t += nw) {
    const float* xp = x + (size_t)t * HDIM;
    float xv[16];
#pragma unroll
    for (int j = 0; j < 16; j++) xv[j] = xp[lane + 64 * j];
    // fused cast: write bf16 row while it's in registers
    unsigned short* xbp = xb + (size_t)t * HDIM;
#pragma unroll
    for (int j = 0; j < 16; j++) xbp[lane + 64 * j] = f2b(xv[j]);
    float lg[8];
#pragma unroll
    for (int e = 0; e < 8; e++) {
      const float* wp = srw + e * HDIM;
      float s = 0.f;
#pragma unroll
      for (int j = 0; j < 16; j++) s += xv[j] * wp[lane + 64 * j];
#pragma unroll
      for (int off = 32; off > 0; off >>= 1) s += __shfl_xor(s, off, 64);
      lg[e] = s;
    }
    int e0 = 0; float l0 = lg[0];
#pragma unroll
    for (int e = 1; e < 8; e++) if (lg[e] > l0) { l0 = lg[e]; e0 = e; }
    int e1 = -1; float l1 = -3.0e38f;
#pragma unroll
    for (int e = 0; e < 8; e++) if (e != e0 && lg[e] > l1) { l1 = lg[e]; e1 = e; }
    float w0 = 1.f / (1.f + __expf(l1 - l0));   // == renormalized top-2 softmax
    if (lane == 0) {
      tok_e[t * 2 + 0] = e0; tok_e[t * 2 + 1] = e1;
      tok_w[t * 2 + 0] = w0; tok_w[t * 2 + 1] = 1.f - w0;
      atomicAdd(&hcnt[e0 * 2 + 0], 1);   // LDS atomic: cheap
      atomicAdd(&hcnt[e1 * 2 + 1], 1);
    }
  }
  __syncthreads();
  if (tid < NEXP * 2) hist[blockIdx.x * 16 + tid] = hcnt[tid];  // plain store
}

// ---------------- scan: sums hist[RBLK][16] -> offs + (e,slot) segments -----
__global__ void scan_kernel(const int* __restrict__ hist, int* __restrict__ offs,
                            int* __restrict__ seg_start, int* __restrict__ seg_len) {
  int lane = threadIdx.x & 63;
  int tot[NEXP * 2];
#pragma unroll
  for (int k = 0; k < NEXP * 2; k++) {
    int s = 0;
    for (int b = lane; b < RBLK; b += 64) s += hist[b * 16 + k];
#pragma unroll
    for (int off = 32; off > 0; off >>= 1) s += __shfl_xor(s, off, 64);
    tot[k] = s;
  }
  if (lane == 0) {
    int s = 0;
#pragma unroll
    for (int e = 0; e < NEXP; e++) {
      offs[e] = s;
      seg_start[e * 2 + 0] = s;             seg_len[e * 2 + 0] = tot[e * 2 + 0];
      seg_start[e * 2 + 1] = s + tot[e * 2]; seg_len[e * 2 + 1] = tot[e * 2 + 1];
      s += tot[e * 2 + 0] + tot[e * 2 + 1];
    }
    offs[NEXP] = s;
  }
}

// ---------------- scatter: block-level range reservation, slot-partitioned ----
__global__ __launch_bounds__(256) void scatter_kernel(const int* __restrict__ tok_e,
                                                      const float* __restrict__ tok_w,
                                                      const int* __restrict__ seg_start,
                                                      int* __restrict__ cursor,
                                                      int* __restrict__ asg_tok,
                                                      float* __restrict__ asg_w) {
  __shared__ int lcnt[NEXP * 2], lbase[NEXP * 2], lpos[NEXP * 2];
  int tid = threadIdx.x;
  if (tid < NEXP * 2) { lcnt[tid] = 0; lpos[tid] = 0; }
  __syncthreads();
  int t = blockIdx.x * 256 + tid;
  int e0 = tok_e[t * 2 + 0], e1 = tok_e[t * 2 + 1];
  float w0 = tok_w[t * 2 + 0], w1 = tok_w[t * 2 + 1];
  int k0 = e0 * 2 + 0, k1 = e1 * 2 + 1;
  atomicAdd(&lcnt[k0], 1);
  atomicAdd(&lcnt[k1], 1);
  __syncthreads();
  if (tid < NEXP * 2) {
    int c = lcnt[tid];
    lbase[tid] = c ? atomicAdd(&cursor[tid], c) : 0;
  }
  __syncthreads();
  int p0 = atomicAdd(&lpos[k0], 1);
  int q0 = seg_start[k0] + lbase[k0] + p0;
  asg_tok[q0] = t; asg_w[q0] = w0;
  int p1 = atomicAdd(&lpos[k1], 1);
  int q1 = seg_start[k1] + lbase[k1] + p1;
  asg_tok[q1] = t; asg_w[q1] = w1;
}

// ---------------- GEMM1: hact = silu(X*Wg^T) * (X*Wu^T) ----------------
// UNCHANGED from round 5 (control). 256x128 tile, 512 thr (8 waves 4Mx2N),
// BK=64, dbuf 128 KB, stage(t+1) inside tile t compute, XOR swizzle (0 confl).
__global__ __launch_bounds__(512, 1) void gemm1_kernel(
    const unsigned short* __restrict__ xb,
    const unsigned short* __restrict__ wg,
    const unsigned short* __restrict__ wu,
    const int* __restrict__ asg_tok,
    const int* __restrict__ offs,
    unsigned short* __restrict__ hact,
    int i0, int ichunk) {
  int nt = blockIdx.x;
  int mt = blockIdx.y;
  int e  = blockIdx.z;
  int base = offs[e];
  int rows = offs[e + 1] - base;
  if (mt * 256 >= rows) return;

  __shared__ __align__(16) unsigned short lA [2][256 * 64];   // 64 KB
  __shared__ __align__(16) unsigned short lBg[2][128 * 64];   // 32 KB
  __shared__ __align__(16) unsigned short lBu[2][128 * 64];   // 32 KB

  int t = threadIdx.x;                  // 0..511
  int lane = t & 63, wid = t >> 6;      // 8 waves
  int wm = wid & 3, wn = wid >> 2;      // 4M x 2N
  int mrow = lane & 15, quad = lane >> 4;
  int row8 = t >> 3;                    // 0..63 staging row within 64-row round
  int csrc = (((t & 7) ^ (row8 & 7)) << 3);   // pre-swizzled source col (shorts)
  int sw   = mrow & 7;                        // read-side swizzle key
  int dst  = t * 8;                           // linear LDS dest (shorts)

  const unsigned short *aP[4], *gP[2], *uP[2];
#pragma unroll
  for (int r = 0; r < 4; r++) {
    int arow = mt * 256 + r * 64 + row8;
    if (arow >= rows) arow = rows - 1;
    aP[r] = xb + (size_t)asg_tok[base + arow] * HDIM + csrc;
  }
#pragma unroll
  for (int r = 0; r < 2; r++) {
    int brow = i0 + nt * 128 + r * 64 + row8;
    gP[r] = wg + ((size_t)e * IDIM + brow) * HDIM + csrc;
    uP[r] = wu + ((size_t)e * IDIM + brow) * HDIM + csrc;
  }

  f32x4 accg[4][4], accu[4][4];
#pragma unroll
  for (int i = 0; i < 4; i++)
#pragma unroll
    for (int j = 0; j < 4; j++) { accg[i][j] = (f32x4)(0.f); accu[i][j] = (f32x4)(0.f); }

#define STG1A(B, K) do {                                   \
    async16(aP[0] + (K), &lA[B][dst]);                     \
    async16(aP[1] + (K), &lA[B][4096 + dst]);              \
    async16(aP[2] + (K), &lA[B][8192 + dst]);              \
    async16(aP[3] + (K), &lA[B][12288 + dst]); } while (0)
#define STG1B(B, K) do {                                   \
    async16(gP[0] + (K), &lBg[B][dst]);                    \
    async16(gP[1] + (K), &lBg[B][4096 + dst]);             \
    async16(uP[0] + (K), &lBu[B][dst]);                    \
    async16(uP[1] + (K), &lBu[B][4096 + dst]); } while (0)

  STG1A(0, 0); STG1B(0, 0);

  for (int kt = 0; kt < HDIM / 64; kt++) {
    int cur = kt & 1;
    asm volatile("s_waitcnt vmcnt(0)" ::: "memory");  // tile kt staged (issued 1 block ago)
    __builtin_amdgcn_s_barrier();
    int nk = (kt + 1) * 64;
    bool pf = (kt + 1) < (HDIM / 64);
#pragma unroll
    for (int kh = 0; kh < 2; kh++) {
      int ko = ((((kh << 2) | quad) ^ sw) << 3);
      bf16x8 af[4], bgf[4];
#pragma unroll
      for (int i = 0; i < 4; i++) {
        af[i]  = load_frag(&lA [cur][(wm * 64 + i * 16 + mrow) * 64 + ko]);
        bgf[i] = load_frag(&lBg[cur][(wn * 64 + i * 16 + mrow) * 64 + ko]);
      }
      if (pf) { if (kh == 0) STG1A(cur ^ 1, nk); else STG1B(cur ^ 1, nk); }
      __builtin_amdgcn_s_setprio(1);
#pragma unroll
      for (int mi = 0; mi < 4; mi++)
#pragma unroll
        for (int ni = 0; ni < 4; ni++)
          accg[mi][ni] = __builtin_amdgcn_mfma_f32_16x16x32_bf16(af[mi], bgf[ni], accg[mi][ni], 0, 0, 0);
      __builtin_amdgcn_s_setprio(0);
      bf16x8 buf2[4];
#pragma unroll
      for (int i = 0; i < 4; i++)
        buf2[i] = load_frag(&lBu[cur][(wn * 64 + i * 16 + mrow) * 64 + ko]);
      __builtin_amdgcn_s_setprio(1);
#pragma unroll
      for (int mi = 0; mi < 4; mi++)
#pragma unroll
        for (int ni = 0; ni < 4; ni++)
          accu[mi][ni] = __builtin_amdgcn_mfma_f32_16x16x32_bf16(af[mi], buf2[ni], accu[mi][ni], 0, 0, 0);
      __builtin_amdgcn_s_setprio(0);
    }
    __builtin_amdgcn_sched_barrier(0);
    __builtin_amdgcn_s_barrier();     // all waves done reading buf[cur]
  }
#undef STG1A
#undef STG1B

  // epilogue: silu(g)*u -> bf16 (hact is [NASG][ichunk], chunk-local cols)
#pragma unroll
  for (int mi = 0; mi < 4; mi++) {
#pragma unroll
    for (int r = 0; r < 4; r++) {
      int row = mt * 256 + wm * 64 + mi * 16 + quad * 4 + r;
      if (row < rows) {
        size_t rb = (size_t)(base + row) * ichunk + nt * 128 + wn * 64;
#pragma unroll
        for (int ni = 0; ni < 4; ni++) {
          float g = accg[mi][ni][r];
          float u = accu[mi][ni][r];
          float h = g / (1.f + __expf(-g)) * u;
          hact[rb + ni * 16 + mrow] = f2b(h);
        }
      }
    }
  }
}

// ---------------- GEMM2: out = / += w * (hact * Wd^T), grouped, NO atomics ----
// Two stream-ordered passes over slot-partitioned segments:
//   pass 0 (slot-0 rows): accum=0 -> plain store (covers every token exactly
//   once, so no d_out memset needed); pass 1 (slot-1 rows): accum=1 ->
//   non-atomic read-add-store (unique writer per token, stream-ordered).
// Replaces 67M fp32 global atomicAdds (~200us of L2 RMW serialization).
// Inner loop identical to round 5.
__global__ __launch_bounds__(512, 1) void gemm2_kernel(
    const unsigned short* __restrict__ hact,
    const unsigned short* __restrict__ wd,
    const int* __restrict__ asg_tok,
    const float* __restrict__ asg_w,
    const int* __restrict__ seg_start,
    const int* __restrict__ seg_len,
    float* __restrict__ out,
    int i0, int ichunk, int pass, int accum) {
  int nt = blockIdx.x;
  int mt = blockIdx.y;
  int e  = blockIdx.z;
  int si = e * 2 + pass;
  int base = seg_start[si];
  int rows = seg_len[si];
  if (mt * 256 >= rows) return;

  __shared__ __align__(16) unsigned short lA[2][256 * 64];   // 64 KB
  __shared__ __align__(16) unsigned short lB[2][256 * 64];   // 64 KB

  int t = threadIdx.x;
  int lane = t & 63, wid = t >> 6;
  int wm = wid & 1, wn = wid >> 1;      // 2M x 4N; wave tile 128 x 64
  int mrow = lane & 15, quad = lane >> 4;
  int row8 = t >> 3;
  int csrc = (((t & 7) ^ (row8 & 7)) << 3);
  int sw   = mrow & 7;
  int dst  = t * 8;

  const unsigned short *aP[4], *bP[4];
#pragma unroll
  for (int r = 0; r < 4; r++) {
    int arow = mt * 256 + r * 64 + row8;
    if (arow >= rows) arow = rows - 1;
    aP[r] = hact + (size_t)(base + arow) * ichunk + csrc;
    int brow = nt * 256 + r * 64 + row8;
    bP[r] = wd + ((size_t)e * HDIM + brow) * IDIM + i0 + csrc;
  }

  f32x4 acc[8][4];
#pragma unroll
  for (int i = 0; i < 8; i++)
#pragma unroll
    for (int j = 0; j < 4; j++) acc[i][j] = (f32x4)(0.f);

#define STG2A(B, K) do {                                   \
    async16(aP[0] + (K), &lA[B][dst]);                     \
    async16(aP[1] + (K), &lA[B][4096 + dst]);              \
    async16(aP[2] + (K), &lA[B][8192 + dst]);              \
    async16(aP[3] + (K), &lA[B][12288 + dst]); } while (0)
#define STG2B(B, K) do {                                   \
    async16(bP[0] + (K), &lB[B][dst]);                     \
    async16(bP[1] + (K), &lB[B][4096 + dst]);              \
    async16(bP[2] + (K), &lB[B][8192 + dst]);              \
    async16(bP[3] + (K), &lB[B][12288 + dst]); } while (0)

  STG2A(0, 0); STG2B(0, 0);

  int NT2 = ichunk / 64;
  for (int kt = 0; kt < NT2; kt++) {
    int cur = kt & 1;
    asm volatile("s_waitcnt vmcnt(0)" ::: "memory");
    __builtin_amdgcn_s_barrier();
    int nk = (kt + 1) * 64;
    bool pf = (kt + 1) < NT2;
#pragma unroll
    for (int kh = 0; kh < 2; kh++) {
      int ko = ((((kh << 2) | quad) ^ sw) << 3);
      bf16x8 af[8], bf[4];
#pragma unroll
      for (int i = 0; i < 8; i++)
        af[i] = load_frag(&lA[cur][(wm * 128 + i * 16 + mrow) * 64 + ko]);
#pragma unroll
      for (int i = 0; i < 4; i++)
        bf[i] = load_frag(&lB[cur][(wn * 64 + i * 16 + mrow) * 64 + ko]);
      if (pf) { if (kh == 0) STG2A(cur ^ 1, nk); else STG2B(cur ^ 1, nk); }
      __builtin_amdgcn_s_setprio(1);
#pragma unroll
      for (int mi = 0; mi < 8; mi++)
#pragma unroll
        for (int ni = 0; ni < 4; ni++)
          acc[mi][ni] = __builtin_amdgcn_mfma_f32_16x16x32_bf16(af[mi], bf[ni], acc[mi][ni], 0, 0, 0);
      __builtin_amdgcn_s_setprio(0);
    }
    __builtin_amdgcn_sched_barrier(0);
    __builtin_amdgcn_s_barrier();
  }
#undef STG2A
#undef STG2B

  // epilogue: scale by routing weight; plain store (accum=0) or read-add-store
#pragma unroll
  for (int mi = 0; mi < 8; mi++) {
#pragma unroll
    for (int r = 0; r < 4; r++) {
      int row = mt * 256 + wm * 128 + mi * 16 + quad * 4 + r;
      if (row < rows) {
        int ar = base + row;
        int tok = asg_tok[ar];
        float w = asg_w[ar];
        float* op = out + (size_t)tok * HDIM + nt * 256 + wn * 64;
        if (accum) {
#pragma unroll
          for (int ni = 0; ni < 4; ni++)
            op[ni * 16 + mrow] += w * acc[mi][ni][r];
        } else {
#pragma unroll
          for (int ni = 0; ni < 4; ni++)
            op[ni * 16 + mrow] = w * acc[mi][ni][r];
        }
      }
    }
  }
}

// ---------------- launch ----------------
extern "C" void kernel_launch(void* const* d_in, const int* in_sizes, int n_in,
                              void* d_out, int out_size, void* d_ws, size_t ws_size,
                              hipStream_t stream) {
  const float* x  = (const float*)d_in[0];
  const float* rw = (const float*)d_in[1];
  const float* gw = (const float*)d_in[2];
  const float* uw = (const float*)d_in[3];
  const float* dw = (const float*)d_in[4];
  float* out = (float*)d_out;
  char* ws = (char*)d_ws;

  // ---- workspace layout (primary path: 235,405,568 B) ----
  unsigned short* wg = (unsigned short*)ws;
  unsigned short* wu = wg + (size_t)NEXP * IDIM * HDIM;
  unsigned short* wd = wu + (size_t)NEXP * IDIM * HDIM;
  char* p = ws + 3ull * NEXP * IDIM * HDIM * 2;
  int*   asg_tok = (int*)p;            p += (size_t)NASG * 4;
  float* asg_w   = (float*)p;          p += (size_t)NASG * 4;
  int*   tok_e   = (int*)p;            p += (size_t)NASG * 4;
  float* tok_w   = (float*)p;          p += (size_t)NASG * 4;
  int*   meta    = (int*)p;            p += 256;
  int* cursor    = meta;          // 16  (per e,slot)
  int* offs      = meta + 16;     // 9
  int* seg_start = meta + 32;     // 16
  int* seg_len   = meta + 48;     // 16

  // hist[RBLK][16] lives at d_out+40MB (dead until gemm2 pass0 writes out;
  // scan consumes it long before that).
  int* hist = (int*)((char*)d_out + (40ull << 20));

  int ichunk; bool xb_in_out;
  if      (ws_size >= 235405568ull) { ichunk = 2048; xb_in_out = true;  }
  else if (ws_size >= 201851136ull) { ichunk = 1024; xb_in_out = false; }
  else if (ws_size >= 168296704ull) { ichunk = 512;  xb_in_out = false; }
  else                              { ichunk = 256;  xb_in_out = false; }

  unsigned short* xb;
  unsigned short* hact;
  if (xb_in_out) {
    xb   = (unsigned short*)d_out;       // first 33.5 MB of the 67 MB output
    hact = (unsigned short*)p;           // 134.2 MB
  } else {
    xb   = (unsigned short*)p;
    hact = (unsigned short*)(p + (size_t)NTOK * HDIM * 2);
  }

  hipMemsetAsync(meta, 0, 64, stream);   // cursor[16]

  // fp32 -> bf16 weight casts (x cast fused into router)
  cast_kernel<<<4096, 256, 0, stream>>>(gw, wg, (NEXP * IDIM * HDIM) / 4);
  cast_kernel<<<4096, 256, 0, stream>>>(uw, wu, (NEXP * IDIM * HDIM) / 4);
  cast_kernel<<<4096, 256, 0, stream>>>(dw, wd, (NEXP * HDIM * IDIM) / 4);

  router_kernel<<<RBLK, 256, 0, stream>>>(x, rw, xb, tok_e, tok_w, hist);
  scan_kernel<<<1, 64, 0, stream>>>(hist, offs, seg_start, seg_len);
  scatter_kernel<<<NTOK / 256, 256, 0, stream>>>(tok_e, tok_w, seg_start, cursor, asg_tok, asg_w);

  // gemm2 grid: y=64 covers worst-case 16384-row segment; blocks early-out.
  if (xb_in_out) {
    gemm1_kernel<<<dim3(16, 128, NEXP), 512, 0, stream>>>(xb, wg, wu, asg_tok, offs, hact, 0, 2048);
    // xb (in d_out) is dead now; pass0 plain-stores cover every token (no memset)
    gemm2_kernel<<<dim3(HDIM / 256, 64, NEXP), 512, 0, stream>>>(hact, wd, asg_tok, asg_w, seg_start, seg_len, out, 0, 2048, 0, 0);
    gemm2_kernel<<<dim3(HDIM / 256, 64, NEXP), 512, 0, stream>>>(hact, wd, asg_tok, asg_w, seg_start, seg_len, out, 0, 2048, 1, 1);
  } else {
    for (int i0 = 0; i0 < IDIM; i0 += ichunk) {
      gemm1_kernel<<<dim3(ichunk / 128, 128, NEXP), 512, 0, stream>>>(xb, wg, wu, asg_tok, offs, hact, i0, ichunk);
      gemm2_kernel<<<dim3(HDIM / 256, 64, NEXP), 512, 0, stream>>>(hact, wd, asg_tok, asg_w, seg_start, seg_len, out, i0, ichunk, 0, i0 > 0 ? 1 : 0);
      gemm2_kernel<<<dim3(HDIM / 256, 64, NEXP), 512, 0, stream>>>(hact, wd, asg_tok, asg_w, seg_start, seg_len, out, i0, ichunk, 1, 1);
    }
  }
}